// Round 1
// baseline (664.574 us; speedup 1.0000x reference)
//
#include <hip/hip_runtime.h>
#include <hip/hip_bf16.h>
#include <math.h>

// Problem constants (DeepseekV3MoE reference)
#define T_TOK 2048
#define H_DIM 1024
#define E_EXP 16
#define K_TOP 4
#define G_GRP 4
#define TG_SEL 2
#define I_SZ 512
#define SCALE_F 2.5f

typedef __attribute__((ext_vector_type(8))) short bfrag;   // 8 bf16 (4 VGPR)
typedef __attribute__((ext_vector_type(4))) float f32x4;   // MFMA acc

__device__ __forceinline__ short f2bf(float f) {
    union { float f; unsigned u; } v; v.f = f;
    unsigned u = v.u;
    u += 0x7fffu + ((u >> 16) & 1u);   // RNE
    return (short)(u >> 16);
}

// ---------------------------------------------------------------- zero
__global__ void zero_kernel(float* __restrict__ out, int n4, int* __restrict__ counts) {
    int i = blockIdx.x * blockDim.x + threadIdx.x;
    if (i < n4) {
        float4 z = {0.f, 0.f, 0.f, 0.f};
        *(float4*)(out + (size_t)i * 4) = z;
    }
    if (blockIdx.x == 0 && threadIdx.x < E_EXP) counts[threadIdx.x] = 0;
}

// ---------------------------------------------------------------- fp32 -> bf16
__global__ void convert_bf16(const float* __restrict__ src, short* __restrict__ dst, int n) {
    int i = (blockIdx.x * blockDim.x + threadIdx.x) * 8;
    if (i >= n) return;
    float4 a = *(const float4*)(src + i);
    float4 b = *(const float4*)(src + i + 4);
    short4 s0 = { f2bf(a.x), f2bf(a.y), f2bf(a.z), f2bf(a.w) };
    short4 s1 = { f2bf(b.x), f2bf(b.y), f2bf(b.z), f2bf(b.w) };
    *(short4*)(dst + i) = s0;
    *(short4*)(dst + i + 4) = s1;
}

// ---------------------------------------------------------------- router
// 1 wave per token. fp32 exact scoring; jax top_k tie semantics (lowest index).
__global__ void router_kernel(const float* __restrict__ x,
                              const float* __restrict__ rw,
                              const float* __restrict__ ebias,
                              int* __restrict__ counts,
                              int* __restrict__ lists,
                              float* __restrict__ lweights) {
    int t = blockIdx.x;
    int lane = threadIdx.x;           // 0..63
    const float* xr = x + (size_t)t * H_DIM + lane * 16;
    float xv[16];
    #pragma unroll
    for (int j = 0; j < 16; ++j) xv[j] = xr[j];

    __shared__ float logit_s[E_EXP];
    for (int e = 0; e < E_EXP; ++e) {
        const float* wr = rw + (size_t)e * H_DIM + lane * 16;
        float acc = 0.f;
        #pragma unroll
        for (int j = 0; j < 16; ++j) acc += xv[j] * wr[j];
        #pragma unroll
        for (int off = 32; off > 0; off >>= 1) acc += __shfl_down(acc, off);
        if (lane == 0) logit_s[e] = acc;
    }
    __syncthreads();
    if (lane != 0) return;

    float scores[E_EXP], sc[E_EXP];
    for (int e = 0; e < E_EXP; ++e) {
        float s = 1.f / (1.f + expf(-logit_s[e]));
        scores[e] = s;
        sc[e] = s + ebias[e];
    }
    // group score: sum of top-2 within each group of 4
    float gs[G_GRP];
    for (int g = 0; g < G_GRP; ++g) {
        float v[4] = { sc[g*4], sc[g*4+1], sc[g*4+2], sc[g*4+3] };
        float b1 = -1e30f; int i1 = -1;
        for (int j = 0; j < 4; ++j) if (v[j] > b1) { b1 = v[j]; i1 = j; }
        float b2 = -1e30f;
        for (int j = 0; j < 4; ++j) if (j != i1 && v[j] > b2) b2 = v[j];
        gs[g] = b1 + b2;
    }
    // top-2 groups (tie -> lower index)
    int g1 = -1; float b1 = -1e30f;
    for (int g = 0; g < G_GRP; ++g) if (gs[g] > b1) { b1 = gs[g]; g1 = g; }
    int g2 = -1; float b2 = -1e30f;
    for (int g = 0; g < G_GRP; ++g) if (g != g1 && gs[g] > b2) { b2 = gs[g]; g2 = g; }

    float masked[E_EXP];
    for (int e = 0; e < E_EXP; ++e) {
        int grp = e >> 2;
        masked[e] = (grp == g1 || grp == g2) ? sc[e] : 0.f;
    }
    // top-4 experts (tie -> lower index)
    int tidx[K_TOP]; float tw[K_TOP];
    for (int k = 0; k < K_TOP; ++k) {
        int bi = -1; float bv = -1e30f;
        for (int e = 0; e < E_EXP; ++e) if (masked[e] > bv) { bv = masked[e]; bi = e; }
        tidx[k] = bi;
        tw[k] = scores[bi];            // gather from unbiased scores
        masked[bi] = -1e30f;
    }
    float sum = tw[0] + tw[1] + tw[2] + tw[3];
    float inv = SCALE_F / (sum + 1e-20f);
    for (int k = 0; k < K_TOP; ++k) {
        int e = tidx[k];
        int pos = atomicAdd(&counts[e], 1);
        lists[e * T_TOK + pos] = t;
        lweights[e * T_TOK + pos] = tw[k] * inv;
    }
}

// ---------------------------------------------------------------- MoE expert GEMM
// block = (expert e in [0,18), 32-token tile). e>=16 -> shared expert halves.
#define TM 32

__device__ __forceinline__ bfrag load_wfrag(const short* p) {
    return *(const bfrag*)p;                 // global_load_dwordx4
}
__device__ __forceinline__ bfrag load_wfrag(const float* p) {
    float4 a = *(const float4*)(p);
    float4 b = *(const float4*)(p + 4);
    bfrag r;
    r[0]=f2bf(a.x); r[1]=f2bf(a.y); r[2]=f2bf(a.z); r[3]=f2bf(a.w);
    r[4]=f2bf(b.x); r[5]=f2bf(b.y); r[6]=f2bf(b.z); r[7]=f2bf(b.w);
    return r;
}

template <typename WT>
__global__ __launch_bounds__(256)
void moe_gemm(const float* __restrict__ x,
              const WT* __restrict__ gate_w, const WT* __restrict__ up_w,
              const WT* __restrict__ down_w, const WT* __restrict__ sh_gate,
              const WT* __restrict__ sh_up, const WT* __restrict__ sh_down,
              const int* __restrict__ counts, const int* __restrict__ lists,
              const float* __restrict__ lweights, float* __restrict__ out) {
    const int bx = blockIdx.x;
    const int e = bx >> 6;          // 64 tiles per expert
    const int tile = bx & 63;

    int ntok; const WT *gp, *upp, *dpp; int dpitch;
    if (e < E_EXP) {
        ntok = counts[e];
        gp  = gate_w + (size_t)e * I_SZ * H_DIM;
        upp = up_w   + (size_t)e * I_SZ * H_DIM;
        dpp = down_w + (size_t)e * H_DIM * I_SZ;
        dpitch = I_SZ;
    } else {
        int s = e - E_EXP;
        ntok = T_TOK;
        gp  = sh_gate + (size_t)s * I_SZ * H_DIM;
        upp = sh_up   + (size_t)s * I_SZ * H_DIM;
        dpp = sh_down + (size_t)s * I_SZ;       // column offset into [H][1024]
        dpitch = 2 * I_SZ;
    }
    const int start = tile * TM;
    if (start >= ntok) return;

    __shared__ __align__(16) short Xs[TM][H_DIM + 8];   // 66 KB, +16B pad vs bank conflicts
    __shared__ __align__(16) short Hs[TM][I_SZ + 8];    // 33 KB
    __shared__ int   toks[TM];
    __shared__ float tws[TM];

    const int tid = threadIdx.x;
    if (tid < TM) {
        int j = start + tid;
        int tok = 0; float w = 0.f;
        if (j < ntok) {
            if (e < E_EXP) { tok = lists[e * T_TOK + j]; w = lweights[e * T_TOK + j]; }
            else           { tok = j;                    w = 1.0f; }
        }
        toks[tid] = tok; tws[tid] = w;
    }
    __syncthreads();

    // stage X tile (fp32 -> bf16)
    {
        int r = tid >> 3;
        int c0 = (tid & 7) * 128;
        const float* xr = x + (size_t)toks[r] * H_DIM + c0;
        #pragma unroll
        for (int c = 0; c < 128; c += 4) {
            float4 v = *(const float4*)(xr + c);
            short4 s = { f2bf(v.x), f2bf(v.y), f2bf(v.z), f2bf(v.w) };
            *(short4*)&Xs[r][c0 + c] = s;
        }
    }
    __syncthreads();

    const int lane = tid & 63;
    const int wv   = tid >> 6;       // 0..3
    const int lr   = lane & 15;
    const int lq   = lane >> 4;
    const int ko   = lq * 8;

    // Phase A: G = X Wg^T, U = X Wu^T, h = silu(G)*U  -> Hs (bf16)
    for (int it = 0; it < I_SZ / 64; ++it) {             // 8 i-tiles per wave
        const int i0 = wv * (I_SZ / 4) + it * 16;
        const WT* grow = gp  + (size_t)(i0 + lr) * H_DIM;
        const WT* urow = upp + (size_t)(i0 + lr) * H_DIM;
        f32x4 aG0 = {0.f,0.f,0.f,0.f}, aU0 = {0.f,0.f,0.f,0.f};
        f32x4 aG1 = {0.f,0.f,0.f,0.f}, aU1 = {0.f,0.f,0.f,0.f};
        for (int k0 = 0; k0 < H_DIM; k0 += 32) {
            bfrag bg = load_wfrag(grow + k0 + ko);
            bfrag bu = load_wfrag(urow + k0 + ko);
            bfrag a0 = *(const bfrag*)&Xs[lr][k0 + ko];
            bfrag a1 = *(const bfrag*)&Xs[lr + 16][k0 + ko];
            aG0 = __builtin_amdgcn_mfma_f32_16x16x32_bf16(a0, bg, aG0, 0, 0, 0);
            aG1 = __builtin_amdgcn_mfma_f32_16x16x32_bf16(a1, bg, aG1, 0, 0, 0);
            aU0 = __builtin_amdgcn_mfma_f32_16x16x32_bf16(a0, bu, aU0, 0, 0, 0);
            aU1 = __builtin_amdgcn_mfma_f32_16x16x32_bf16(a1, bu, aU1, 0, 0, 0);
        }
        #pragma unroll
        for (int r = 0; r < 4; ++r) {
            const int trow = lq * 4 + r;
            float g0 = aG0[r], u0 = aU0[r];
            Hs[trow][i0 + lr] = f2bf(g0 * u0 / (1.f + __expf(-g0)));
            float g1 = aG1[r], u1 = aU1[r];
            Hs[trow + 16][i0 + lr] = f2bf(g1 * u1 / (1.f + __expf(-g1)));
        }
    }
    __syncthreads();

    // Phase B: Y = h Wd^T, scaled accumulate into out
    for (int ct = 0; ct < H_DIM / 64; ++ct) {            // 16 col-tiles per wave
        const int c0 = wv * (H_DIM / 4) + ct * 16;
        const WT* drow = dpp + (size_t)(c0 + lr) * dpitch;
        f32x4 a0 = {0.f,0.f,0.f,0.f}, a1 = {0.f,0.f,0.f,0.f};
        for (int k0 = 0; k0 < I_SZ; k0 += 32) {
            bfrag bd = load_wfrag(drow + k0 + ko);
            bfrag h0 = *(const bfrag*)&Hs[lr][k0 + ko];
            bfrag h1 = *(const bfrag*)&Hs[lr + 16][k0 + ko];
            a0 = __builtin_amdgcn_mfma_f32_16x16x32_bf16(h0, bd, a0, 0, 0, 0);
            a1 = __builtin_amdgcn_mfma_f32_16x16x32_bf16(h1, bd, a1, 0, 0, 0);
        }
        #pragma unroll
        for (int r = 0; r < 4; ++r) {
            const int trow = lq * 4 + r;
            float w0 = tws[trow], w1 = tws[trow + 16];
            if (w0 != 0.f) atomicAdd(out + (size_t)toks[trow] * H_DIM + c0 + lr, a0[r] * w0);
            if (w1 != 0.f) atomicAdd(out + (size_t)toks[trow + 16] * H_DIM + c0 + lr, a1[r] * w1);
        }
    }
}

// ---------------------------------------------------------------- launch
extern "C" void kernel_launch(void* const* d_in, const int* in_sizes, int n_in,
                              void* d_out, int out_size, void* d_ws, size_t ws_size,
                              hipStream_t stream) {
    const float* x     = (const float*)d_in[0];
    const float* rw    = (const float*)d_in[1];
    const float* ebias = (const float*)d_in[2];
    const float* gate_w = (const float*)d_in[3];
    const float* up_w   = (const float*)d_in[4];
    const float* down_w = (const float*)d_in[5];
    const float* shg    = (const float*)d_in[6];
    const float* shu    = (const float*)d_in[7];
    const float* shd    = (const float*)d_in[8];
    float* out = (float*)d_out;

    char* ws = (char*)d_ws;
    int*   counts = (int*)ws;                       // 16 ints
    int*   lists  = (int*)(ws + 1024);              // 16*2048 ints  = 128 KB
    float* lw     = (float*)(ws + 1024 + 131072);   // 16*2048 float = 128 KB
    size_t WOFF = 1024 + 131072 + 131072;           // 263168, 256-aligned

    const size_t n_gu   = (size_t)E_EXP * I_SZ * H_DIM;   // 8388608 per tensor
    const size_t n_sh   = (size_t)H_DIM * 1024;           // 1048576 per tensor
    size_t need = WOFF + (3 * n_gu + 3 * n_sh) * sizeof(short);

    // zero out + counts
    zero_kernel<<<(out_size / 4 + 255) / 256, 256, 0, stream>>>(out, out_size / 4, counts);
    router_kernel<<<T_TOK, 64, 0, stream>>>(x, rw, ebias, counts, lists, lw);

    const int grid = (E_EXP + 2) * 64;   // 18 experts x 64 tiles

    if (ws_size >= need) {
        short* g_bf  = (short*)(ws + WOFF);
        short* u_bf  = g_bf + n_gu;
        short* d_bf  = u_bf + n_gu;
        short* sg_bf = d_bf + n_gu;
        short* su_bf = sg_bf + n_sh;
        short* sd_bf = su_bf + n_sh;
        int gb = (int)(n_gu / 8 / 256);
        int sb = (int)(n_sh / 8 / 256);
        convert_bf16<<<gb, 256, 0, stream>>>(gate_w, g_bf, (int)n_gu);
        convert_bf16<<<gb, 256, 0, stream>>>(up_w,   u_bf, (int)n_gu);
        convert_bf16<<<gb, 256, 0, stream>>>(down_w, d_bf, (int)n_gu);
        convert_bf16<<<sb, 256, 0, stream>>>(shg, sg_bf, (int)n_sh);
        convert_bf16<<<sb, 256, 0, stream>>>(shu, su_bf, (int)n_sh);
        convert_bf16<<<sb, 256, 0, stream>>>(shd, sd_bf, (int)n_sh);
        moe_gemm<short><<<grid, 256, 0, stream>>>(x, g_bf, u_bf, d_bf, sg_bf, su_bf, sd_bf,
                                                  counts, lists, lw, out);
    } else {
        moe_gemm<float><<<grid, 256, 0, stream>>>(x, gate_w, up_w, down_w, shg, shu, shd,
                                                  counts, lists, lw, out);
    }
}

// Round 2
// 357.408 us; speedup vs baseline: 1.8594x; 1.8594x over previous
//
#include <hip/hip_runtime.h>
#include <hip/hip_bf16.h>
#include <math.h>

// Problem constants (DeepseekV3MoE reference)
#define T_TOK 2048
#define H_DIM 1024
#define E_EXP 16
#define K_TOP 4
#define G_GRP 4
#define I_SZ 512
#define SCALE_F 2.5f

typedef __attribute__((ext_vector_type(8))) short bfrag;    // 8 bf16 (4 VGPR)
typedef __attribute__((ext_vector_type(8))) short short8v;
typedef __attribute__((ext_vector_type(4))) float f32x4;    // MFMA acc

#define MFMA16(a, b, c) __builtin_amdgcn_mfma_f32_16x16x32_bf16(a, b, c, 0, 0, 0)

__device__ __forceinline__ short f2bf(float f) {
    union { float f; unsigned u; } v; v.f = f;
    unsigned u = v.u;
    u += 0x7fffu + ((u >> 16) & 1u);   // RNE
    return (short)(u >> 16);
}

// XOR-swizzled LDS index for 64-short rows: 8 segments of 8 shorts (16 B),
// physical segment = logical_seg ^ (row & 7).  Conflict-free for both the
// staging ds_write_b128 and the fragment ds_read_b128 patterns.
__device__ __forceinline__ int lds_idx(int row, int k) {
    return row * 64 + ((((k >> 3) ^ (row & 7))) << 3) + (k & 7);
}

// ---------------------------------------------------------------- fused fp32->bf16 convert
// regions (elems): gate 8388608 | up 8388608 | down 8388608 | shg 1048576 |
//                  shu 1048576 | shd 1048576 | x 2097152   -> total 30408704
__global__ __launch_bounds__(256) void convert_all(
        const float* __restrict__ g, const float* __restrict__ u, const float* __restrict__ d,
        const float* __restrict__ sg, const float* __restrict__ su, const float* __restrict__ sd,
        const float* __restrict__ x,
        short* __restrict__ go, short* __restrict__ uo, short* __restrict__ dd,
        short* __restrict__ sgo, short* __restrict__ suo, short* __restrict__ sdo,
        short* __restrict__ xo) {
    long i = ((long)blockIdx.x * 256 + threadIdx.x) * 8;
    const float* src; short* dst; long off;
    if      (i < 8388608)  { src = g;  dst = go;  off = i; }
    else if (i < 16777216) { src = u;  dst = uo;  off = i - 8388608; }
    else if (i < 25165824) { src = d;  dst = dd;  off = i - 16777216; }
    else if (i < 26214400) { src = sg; dst = sgo; off = i - 25165824; }
    else if (i < 27262976) { src = su; dst = suo; off = i - 26214400; }
    else if (i < 28311552) { src = sd; dst = sdo; off = i - 27262976; }
    else if (i < 30408704) { src = x;  dst = xo;  off = i - 28311552; }
    else return;
    float4 a = *(const float4*)(src + off);
    float4 b = *(const float4*)(src + off + 4);
    short4 s0 = { f2bf(a.x), f2bf(a.y), f2bf(a.z), f2bf(a.w) };
    short4 s1 = { f2bf(b.x), f2bf(b.y), f2bf(b.z), f2bf(b.w) };
    *(short4*)(dst + off) = s0;
    *(short4*)(dst + off + 4) = s1;
}

// ---------------------------------------------------------------- router
// 1 wave per token. fp32 exact scoring; jax top_k tie semantics (lowest index).
__global__ void router_kernel(const float* __restrict__ x,
                              const float* __restrict__ rw,
                              const float* __restrict__ ebias,
                              int* __restrict__ counts,
                              int* __restrict__ lists,
                              float* __restrict__ lweights) {
    int t = blockIdx.x;
    int lane = threadIdx.x;           // 0..63
    const float* xr = x + (size_t)t * H_DIM + lane * 16;
    float xv[16];
    #pragma unroll
    for (int j = 0; j < 16; ++j) xv[j] = xr[j];

    __shared__ float logit_s[E_EXP];
    for (int e = 0; e < E_EXP; ++e) {
        const float* wr = rw + (size_t)e * H_DIM + lane * 16;
        float acc = 0.f;
        #pragma unroll
        for (int j = 0; j < 16; ++j) acc += xv[j] * wr[j];
        #pragma unroll
        for (int off = 32; off > 0; off >>= 1) acc += __shfl_down(acc, off);
        if (lane == 0) logit_s[e] = acc;
    }
    __syncthreads();
    if (lane != 0) return;

    float scores[E_EXP], sc[E_EXP];
    for (int e = 0; e < E_EXP; ++e) {
        float s = 1.f / (1.f + expf(-logit_s[e]));
        scores[e] = s;
        sc[e] = s + ebias[e];
    }
    float gs[G_GRP];
    for (int g = 0; g < G_GRP; ++g) {
        float v[4] = { sc[g*4], sc[g*4+1], sc[g*4+2], sc[g*4+3] };
        float b1 = -1e30f; int i1 = -1;
        for (int j = 0; j < 4; ++j) if (v[j] > b1) { b1 = v[j]; i1 = j; }
        float b2 = -1e30f;
        for (int j = 0; j < 4; ++j) if (j != i1 && v[j] > b2) b2 = v[j];
        gs[g] = b1 + b2;
    }
    int g1 = -1; float b1 = -1e30f;
    for (int g = 0; g < G_GRP; ++g) if (gs[g] > b1) { b1 = gs[g]; g1 = g; }
    int g2 = -1; float b2 = -1e30f;
    for (int g = 0; g < G_GRP; ++g) if (g != g1 && gs[g] > b2) { b2 = gs[g]; g2 = g; }

    float masked[E_EXP];
    for (int e = 0; e < E_EXP; ++e) {
        int grp = e >> 2;
        masked[e] = (grp == g1 || grp == g2) ? sc[e] : 0.f;
    }
    int tidx[K_TOP]; float tw[K_TOP];
    for (int k = 0; k < K_TOP; ++k) {
        int bi = -1; float bv = -1e30f;
        for (int e = 0; e < E_EXP; ++e) if (masked[e] > bv) { bv = masked[e]; bi = e; }
        tidx[k] = bi;
        tw[k] = scores[bi];
        masked[bi] = -1e30f;
    }
    float sum = tw[0] + tw[1] + tw[2] + tw[3];
    float inv = SCALE_F / (sum + 1e-20f);
    for (int k = 0; k < K_TOP; ++k) {
        int e = tidx[k];
        int pos = atomicAdd(&counts[e], 1);
        lists[e * T_TOK + pos] = t;
        lweights[e * T_TOK + pos] = tw[k] * inv;
    }
}

// ---------------------------------------------------------------- Kernel A: gate+up+silu -> h (bf16)
// block = 64 tokens x 64 i-cols, K=1024 in 64-chunks through LDS.
// bx < 4096: routed (e=bx>>8, mt=(bx>>3)&31, nt=bx&7); else shared (512 blocks).
__global__ __launch_bounds__(256)
void moe_gateup(const short* __restrict__ Xbf,
                const int* __restrict__ counts, const int* __restrict__ lists,
                const short* __restrict__ gw, const short* __restrict__ uw,
                const short* __restrict__ sgw, const short* __restrict__ suw,
                short* __restrict__ h_r, short* __restrict__ h_sh) {
    __shared__ __align__(16) short Xs[64*64], Gs[64*64], Us[64*64];
    __shared__ int toks[64];
    const int bx = blockIdx.x, tid = threadIdx.x;
    const short *gbase, *ubase; short* hout; int hpitch;
    if (bx < 4096) {
        int e = bx >> 8, mt = (bx >> 3) & 31, nt = bx & 7;
        int cnt = counts[e];
        if (mt * 64 >= cnt) return;
        if (tid < 64) {
            int j = mt * 64 + tid;
            toks[tid] = (j < cnt) ? lists[e * T_TOK + j] : lists[e * T_TOK];
        }
        gbase = gw + (size_t)e * I_SZ * H_DIM + (size_t)(nt * 64) * H_DIM;
        ubase = uw + (size_t)e * I_SZ * H_DIM + (size_t)(nt * 64) * H_DIM;
        hout  = h_r + ((size_t)e * T_TOK + mt * 64) * I_SZ + nt * 64;
        hpitch = I_SZ;
    } else {
        int b2 = bx - 4096, mt = b2 >> 4, nt = b2 & 15;
        if (tid < 64) toks[tid] = mt * 64 + tid;
        gbase = sgw + (size_t)(nt * 64) * H_DIM;
        ubase = suw + (size_t)(nt * 64) * H_DIM;
        hout  = h_sh + (size_t)(mt * 64) * 1024 + nt * 64;
        hpitch = 1024;
    }
    __syncthreads();

    const int lane = tid & 63, wv = tid >> 6;
    const int mw = wv & 1, nw = wv >> 1;
    const int lr = lane & 15, lq = lane >> 4;

    f32x4 accG[2][2], accU[2][2];
    #pragma unroll
    for (int a = 0; a < 2; ++a)
        #pragma unroll
        for (int b = 0; b < 2; ++b) {
            accG[a][b] = (f32x4){0.f,0.f,0.f,0.f};
            accU[a][b] = (f32x4){0.f,0.f,0.f,0.f};
        }

    const int srow = tid >> 2, s2 = tid & 3;
    const short* xrow = Xbf + (size_t)toks[srow] * H_DIM + s2 * 16;
    const short* grow = gbase + (size_t)srow * H_DIM + s2 * 16;
    const short* urow = ubase + (size_t)srow * H_DIM + s2 * 16;
    const int st0 = lds_idx(srow, s2 * 16);
    const int st1 = lds_idx(srow, s2 * 16 + 8);

    for (int kc = 0; kc < H_DIM; kc += 64) {
        short8v xa = *(const short8v*)(xrow + kc);
        short8v xb = *(const short8v*)(xrow + kc + 8);
        short8v ga = *(const short8v*)(grow + kc);
        short8v gb = *(const short8v*)(grow + kc + 8);
        short8v ua = *(const short8v*)(urow + kc);
        short8v ub = *(const short8v*)(urow + kc + 8);
        __syncthreads();
        *(short8v*)&Xs[st0] = xa; *(short8v*)&Xs[st1] = xb;
        *(short8v*)&Gs[st0] = ga; *(short8v*)&Gs[st1] = gb;
        *(short8v*)&Us[st0] = ua; *(short8v*)&Us[st1] = ub;
        __syncthreads();
        #pragma unroll
        for (int kk = 0; kk < 64; kk += 32) {
            const int kf = kk + lq * 8;
            bfrag a0 = *(const bfrag*)&Xs[lds_idx(mw*32 + lr,      kf)];
            bfrag a1 = *(const bfrag*)&Xs[lds_idx(mw*32 + 16 + lr, kf)];
            bfrag g0 = *(const bfrag*)&Gs[lds_idx(nw*32 + lr,      kf)];
            bfrag g1 = *(const bfrag*)&Gs[lds_idx(nw*32 + 16 + lr, kf)];
            bfrag u0 = *(const bfrag*)&Us[lds_idx(nw*32 + lr,      kf)];
            bfrag u1 = *(const bfrag*)&Us[lds_idx(nw*32 + 16 + lr, kf)];
            accG[0][0] = MFMA16(a0, g0, accG[0][0]);
            accG[0][1] = MFMA16(a0, g1, accG[0][1]);
            accG[1][0] = MFMA16(a1, g0, accG[1][0]);
            accG[1][1] = MFMA16(a1, g1, accG[1][1]);
            accU[0][0] = MFMA16(a0, u0, accU[0][0]);
            accU[0][1] = MFMA16(a0, u1, accU[0][1]);
            accU[1][0] = MFMA16(a1, u0, accU[1][0]);
            accU[1][1] = MFMA16(a1, u1, accU[1][1]);
        }
    }

    #pragma unroll
    for (int fm = 0; fm < 2; ++fm)
        #pragma unroll
        for (int fn = 0; fn < 2; ++fn)
            #pragma unroll
            for (int r = 0; r < 4; ++r) {
                int trow = mw*32 + fm*16 + lq*4 + r;
                int col  = nw*32 + fn*16 + lr;
                float g = accG[fm][fn][r], u = accU[fm][fn][r];
                hout[(size_t)trow * hpitch + col] = f2bf(g * u / (1.f + __expf(-g)));
            }
}

// ---------------------------------------------------------------- Kernel B: down-proj
// mode 1 (shared): K=1024, plain store of full output (runs FIRST).
// mode 0 (routed): K=512, atomicAdd scaled by routing weight.
__global__ __launch_bounds__(256)
void moe_down(const short* __restrict__ h_r, const short* __restrict__ h_sh,
              const int* __restrict__ counts, const int* __restrict__ lists,
              const float* __restrict__ lw, const short* __restrict__ dw,
              const short* __restrict__ shdw, float* __restrict__ out, int mode) {
    __shared__ __align__(16) short Hs[64*64], Ws[64*64];
    __shared__ int toks[64];
    __shared__ float tws[64];
    const int bx = blockIdx.x, tid = threadIdx.x;
    const short *abase, *bbase; int apitch, bpitch, K, n0;
    if (mode == 0) {
        int e = bx >> 9, mt = (bx >> 4) & 31, nt = bx & 15;
        int cnt = counts[e];
        if (mt * 64 >= cnt) return;
        if (tid < 64) {
            int j = mt * 64 + tid;
            toks[tid] = (j < cnt) ? lists[e * T_TOK + j] : 0;
            tws[tid]  = (j < cnt) ? lw[e * T_TOK + j] : 0.f;
        }
        abase = h_r + ((size_t)e * T_TOK + mt * 64) * I_SZ;
        bbase = dw + (size_t)e * H_DIM * I_SZ + (size_t)(nt * 64) * I_SZ;
        apitch = I_SZ; bpitch = I_SZ; K = I_SZ; n0 = nt * 64;
    } else {
        int mt = bx >> 4, nt = bx & 15;
        if (tid < 64) { toks[tid] = mt * 64 + tid; tws[tid] = 1.f; }
        abase = h_sh + (size_t)(mt * 64) * 1024;
        bbase = shdw + (size_t)(nt * 64) * 1024;
        apitch = 1024; bpitch = 1024; K = 1024; n0 = nt * 64;
    }
    __syncthreads();

    const int lane = tid & 63, wv = tid >> 6;
    const int mw = wv & 1, nw = wv >> 1;
    const int lr = lane & 15, lq = lane >> 4;

    f32x4 acc[2][2];
    #pragma unroll
    for (int a = 0; a < 2; ++a)
        #pragma unroll
        for (int b = 0; b < 2; ++b) acc[a][b] = (f32x4){0.f,0.f,0.f,0.f};

    const int srow = tid >> 2, s2 = tid & 3;
    const short* arow = abase + (size_t)srow * apitch + s2 * 16;
    const short* brow = bbase + (size_t)srow * bpitch + s2 * 16;
    const int st0 = lds_idx(srow, s2 * 16);
    const int st1 = lds_idx(srow, s2 * 16 + 8);

    for (int kc = 0; kc < K; kc += 64) {
        short8v ha = *(const short8v*)(arow + kc);
        short8v hb = *(const short8v*)(arow + kc + 8);
        short8v wa = *(const short8v*)(brow + kc);
        short8v wb = *(const short8v*)(brow + kc + 8);
        __syncthreads();
        *(short8v*)&Hs[st0] = ha; *(short8v*)&Hs[st1] = hb;
        *(short8v*)&Ws[st0] = wa; *(short8v*)&Ws[st1] = wb;
        __syncthreads();
        #pragma unroll
        for (int kk = 0; kk < 64; kk += 32) {
            const int kf = kk + lq * 8;
            bfrag a0 = *(const bfrag*)&Hs[lds_idx(mw*32 + lr,      kf)];
            bfrag a1 = *(const bfrag*)&Hs[lds_idx(mw*32 + 16 + lr, kf)];
            bfrag b0 = *(const bfrag*)&Ws[lds_idx(nw*32 + lr,      kf)];
            bfrag b1 = *(const bfrag*)&Ws[lds_idx(nw*32 + 16 + lr, kf)];
            acc[0][0] = MFMA16(a0, b0, acc[0][0]);
            acc[0][1] = MFMA16(a0, b1, acc[0][1]);
            acc[1][0] = MFMA16(a1, b0, acc[1][0]);
            acc[1][1] = MFMA16(a1, b1, acc[1][1]);
        }
    }

    #pragma unroll
    for (int fm = 0; fm < 2; ++fm)
        #pragma unroll
        for (int fn = 0; fn < 2; ++fn)
            #pragma unroll
            for (int r = 0; r < 4; ++r) {
                int trow = mw*32 + fm*16 + lq*4 + r;
                int col  = n0 + nw*32 + fn*16 + lr;
                float v = acc[fm][fn][r];
                if (mode == 0) {
                    float w = tws[trow];
                    if (w != 0.f)
                        atomicAdd(out + (size_t)toks[trow] * H_DIM + col, v * w);
                } else {
                    out[(size_t)toks[trow] * H_DIM + col] = v;
                }
            }
}

// ---------------------------------------------------------------- fallback (fused, fp32 weights)
__global__ void zero_kernel(float* __restrict__ out, int n4, int* __restrict__ counts) {
    int i = blockIdx.x * blockDim.x + threadIdx.x;
    if (i < n4) {
        float4 z = {0.f, 0.f, 0.f, 0.f};
        *(float4*)(out + (size_t)i * 4) = z;
    }
    if (blockIdx.x == 0 && threadIdx.x < E_EXP) counts[threadIdx.x] = 0;
}

__device__ __forceinline__ bfrag load_wfrag_f(const float* p) {
    float4 a = *(const float4*)(p);
    float4 b = *(const float4*)(p + 4);
    bfrag r;
    r[0]=f2bf(a.x); r[1]=f2bf(a.y); r[2]=f2bf(a.z); r[3]=f2bf(a.w);
    r[4]=f2bf(b.x); r[5]=f2bf(b.y); r[6]=f2bf(b.z); r[7]=f2bf(b.w);
    return r;
}

#define TM 32
__global__ __launch_bounds__(256)
void moe_gemm_fb(const float* __restrict__ x,
                 const float* __restrict__ gate_w, const float* __restrict__ up_w,
                 const float* __restrict__ down_w, const float* __restrict__ sh_gate,
                 const float* __restrict__ sh_up, const float* __restrict__ sh_down,
                 const int* __restrict__ counts, const int* __restrict__ lists,
                 const float* __restrict__ lweights, float* __restrict__ out) {
    const int bx = blockIdx.x;
    const int e = bx >> 6;
    const int tile = bx & 63;
    int ntok; const float *gp, *upp, *dpp; int dpitch;
    if (e < E_EXP) {
        ntok = counts[e];
        gp  = gate_w + (size_t)e * I_SZ * H_DIM;
        upp = up_w   + (size_t)e * I_SZ * H_DIM;
        dpp = down_w + (size_t)e * H_DIM * I_SZ;
        dpitch = I_SZ;
    } else {
        int s = e - E_EXP;
        ntok = T_TOK;
        gp  = sh_gate + (size_t)s * I_SZ * H_DIM;
        upp = sh_up   + (size_t)s * I_SZ * H_DIM;
        dpp = sh_down + (size_t)s * I_SZ;
        dpitch = 2 * I_SZ;
    }
    const int start = tile * TM;
    if (start >= ntok) return;

    __shared__ __align__(16) short Xs2[TM][H_DIM + 8];
    __shared__ __align__(16) short Hs2[TM][I_SZ + 8];
    __shared__ int   toks[TM];
    __shared__ float tws[TM];

    const int tid = threadIdx.x;
    if (tid < TM) {
        int j = start + tid;
        int tok = 0; float w = 0.f;
        if (j < ntok) {
            if (e < E_EXP) { tok = lists[e * T_TOK + j]; w = lweights[e * T_TOK + j]; }
            else           { tok = j;                    w = 1.0f; }
        }
        toks[tid] = tok; tws[tid] = w;
    }
    __syncthreads();
    {
        int r = tid >> 3;
        int c0 = (tid & 7) * 128;
        const float* xr = x + (size_t)toks[r] * H_DIM + c0;
        #pragma unroll
        for (int c = 0; c < 128; c += 4) {
            float4 v = *(const float4*)(xr + c);
            short4 s = { f2bf(v.x), f2bf(v.y), f2bf(v.z), f2bf(v.w) };
            *(short4*)&Xs2[r][c0 + c] = s;
        }
    }
    __syncthreads();

    const int lane = tid & 63;
    const int wv   = tid >> 6;
    const int lr   = lane & 15;
    const int lq   = lane >> 4;
    const int ko   = lq * 8;

    for (int it = 0; it < I_SZ / 64; ++it) {
        const int i0 = wv * (I_SZ / 4) + it * 16;
        const float* grow = gp  + (size_t)(i0 + lr) * H_DIM;
        const float* urow = upp + (size_t)(i0 + lr) * H_DIM;
        f32x4 aG0 = {0.f,0.f,0.f,0.f}, aU0 = {0.f,0.f,0.f,0.f};
        f32x4 aG1 = {0.f,0.f,0.f,0.f}, aU1 = {0.f,0.f,0.f,0.f};
        for (int k0 = 0; k0 < H_DIM; k0 += 32) {
            bfrag bg = load_wfrag_f(grow + k0 + ko);
            bfrag bu = load_wfrag_f(urow + k0 + ko);
            bfrag a0 = *(const bfrag*)&Xs2[lr][k0 + ko];
            bfrag a1 = *(const bfrag*)&Xs2[lr + 16][k0 + ko];
            aG0 = MFMA16(a0, bg, aG0);
            aG1 = MFMA16(a1, bg, aG1);
            aU0 = MFMA16(a0, bu, aU0);
            aU1 = MFMA16(a1, bu, aU1);
        }
        #pragma unroll
        for (int r = 0; r < 4; ++r) {
            const int trow = lq * 4 + r;
            float g0 = aG0[r], u0 = aU0[r];
            Hs2[trow][i0 + lr] = f2bf(g0 * u0 / (1.f + __expf(-g0)));
            float g1 = aG1[r], u1 = aU1[r];
            Hs2[trow + 16][i0 + lr] = f2bf(g1 * u1 / (1.f + __expf(-g1)));
        }
    }
    __syncthreads();

    for (int ct = 0; ct < H_DIM / 64; ++ct) {
        const int c0 = wv * (H_DIM / 4) + ct * 16;
        const float* drow = dpp + (size_t)(c0 + lr) * dpitch;
        f32x4 a0 = {0.f,0.f,0.f,0.f}, a1 = {0.f,0.f,0.f,0.f};
        for (int k0 = 0; k0 < I_SZ; k0 += 32) {
            bfrag bd = load_wfrag_f(drow + k0 + ko);
            bfrag h0 = *(const bfrag*)&Hs2[lr][k0 + ko];
            bfrag h1 = *(const bfrag*)&Hs2[lr + 16][k0 + ko];
            a0 = MFMA16(h0, bd, a0);
            a1 = MFMA16(h1, bd, a1);
        }
        #pragma unroll
        for (int r = 0; r < 4; ++r) {
            const int trow = lq * 4 + r;
            float w0 = tws[trow], w1 = tws[trow + 16];
            if (w0 != 0.f) atomicAdd(out + (size_t)toks[trow] * H_DIM + c0 + lr, a0[r] * w0);
            if (w1 != 0.f) atomicAdd(out + (size_t)toks[trow + 16] * H_DIM + c0 + lr, a1[r] * w1);
        }
    }
}

// ---------------------------------------------------------------- launch
extern "C" void kernel_launch(void* const* d_in, const int* in_sizes, int n_in,
                              void* d_out, int out_size, void* d_ws, size_t ws_size,
                              hipStream_t stream) {
    const float* x     = (const float*)d_in[0];
    const float* rw    = (const float*)d_in[1];
    const float* ebias = (const float*)d_in[2];
    const float* gate_w = (const float*)d_in[3];
    const float* up_w   = (const float*)d_in[4];
    const float* down_w = (const float*)d_in[5];
    const float* shg    = (const float*)d_in[6];
    const float* shu    = (const float*)d_in[7];
    const float* shd    = (const float*)d_in[8];
    float* out = (float*)d_out;

    char* ws = (char*)d_ws;
    int*   counts = (int*)ws;                       // 64 B used
    int*   lists  = (int*)(ws + 1024);              // 16*2048 ints  = 128 KB
    float* lw     = (float*)(ws + 1024 + 131072);   // 16*2048 float = 128 KB
    size_t off = 1024 + 131072 + 131072;            // 263168

    const size_t n_gu = (size_t)E_EXP * I_SZ * H_DIM;   // 8388608
    const size_t n_sh = (size_t)H_DIM * 1024;           // 1048576
    const size_t n_x  = (size_t)T_TOK * H_DIM;          // 2097152

    short* g_bf  = (short*)(ws + off); off += n_gu * 2;
    short* u_bf  = (short*)(ws + off); off += n_gu * 2;
    short* d_bf  = (short*)(ws + off); off += n_gu * 2;
    short* sg_bf = (short*)(ws + off); off += n_sh * 2;
    short* su_bf = (short*)(ws + off); off += n_sh * 2;
    short* sd_bf = (short*)(ws + off); off += n_sh * 2;
    short* x_bf  = (short*)(ws + off); off += n_x * 2;
    short* h_r   = (short*)(ws + off); off += (size_t)E_EXP * T_TOK * I_SZ * 2;  // 32 MB
    short* h_sh  = (short*)(ws + off); off += (size_t)T_TOK * 1024 * 2;          // 4 MB
    const size_t need = off;

    if (ws_size >= need) {
        hipMemsetAsync(counts, 0, 64, stream);
        convert_all<<<14848, 256, 0, stream>>>(gate_w, up_w, down_w, shg, shu, shd, x,
                                               g_bf, u_bf, d_bf, sg_bf, su_bf, sd_bf, x_bf);
        router_kernel<<<T_TOK, 64, 0, stream>>>(x, rw, ebias, counts, lists, lw);
        moe_gateup<<<4096 + 512, 256, 0, stream>>>(x_bf, counts, lists, g_bf, u_bf,
                                                   sg_bf, su_bf, h_r, h_sh);
        // shared first (plain store initializes out), then routed (atomicAdd)
        moe_down<<<512, 256, 0, stream>>>(h_r, h_sh, counts, lists, lw, d_bf, sd_bf, out, 1);
        moe_down<<<8192, 256, 0, stream>>>(h_r, h_sh, counts, lists, lw, d_bf, sd_bf, out, 0);
    } else {
        zero_kernel<<<(out_size / 4 + 255) / 256, 256, 0, stream>>>(out, out_size / 4, counts);
        router_kernel<<<T_TOK, 64, 0, stream>>>(x, rw, ebias, counts, lists, lw);
        moe_gemm_fb<<<(E_EXP + 2) * 64, 256, 0, stream>>>(x, gate_w, up_w, down_w,
                                                          shg, shu, shd, counts, lists, lw, out);
    }
}

// Round 3
// 289.954 us; speedup vs baseline: 2.2920x; 1.2326x over previous
//
#include <hip/hip_runtime.h>
#include <hip/hip_bf16.h>
#include <math.h>

// Problem constants (DeepseekV3MoE reference)
#define T_TOK 2048
#define H_DIM 1024
#define E_EXP 16
#define K_TOP 4
#define G_GRP 4
#define I_SZ 512
#define SCALE_F 2.5f

typedef __attribute__((ext_vector_type(8))) short bfrag;    // 8 bf16 (4 VGPR)
typedef __attribute__((ext_vector_type(8))) short short8v;
typedef __attribute__((ext_vector_type(4))) float f32x4;    // MFMA acc

#define MFMA16(a, b, c) __builtin_amdgcn_mfma_f32_16x16x32_bf16(a, b, c, 0, 0, 0)

__device__ __forceinline__ short f2bf(float f) {
    union { float f; unsigned u; } v; v.f = f;
    unsigned u = v.u;
    u += 0x7fffu + ((u >> 16) & 1u);   // RNE
    return (short)(u >> 16);
}

// XOR-swizzled LDS index for 64-short rows: 8 segments of 8 shorts (16 B),
// physical segment = logical_seg ^ (row & 7).  Conflict-free for both the
// staging ds_write_b128 and the fragment ds_read_b128 patterns.
__device__ __forceinline__ int lds_idx(int row, int k) {
    return row * 64 + ((((k >> 3) ^ (row & 7))) << 3) + (k & 7);
}

// ---------------------------------------------------------------- fused fp32->bf16 convert
// regions (elems): gate 8388608 | up 8388608 | down 8388608 | shg 1048576 |
//                  shu 1048576 | shd 1048576 | x 2097152   -> total 30408704
__global__ __launch_bounds__(256) void convert_all(
        const float* __restrict__ g, const float* __restrict__ u, const float* __restrict__ d,
        const float* __restrict__ sg, const float* __restrict__ su, const float* __restrict__ sd,
        const float* __restrict__ x,
        short* __restrict__ go, short* __restrict__ uo, short* __restrict__ dd,
        short* __restrict__ sgo, short* __restrict__ suo, short* __restrict__ sdo,
        short* __restrict__ xo) {
    long i = ((long)blockIdx.x * 256 + threadIdx.x) * 8;
    const float* src; short* dst; long off;
    if      (i < 8388608)  { src = g;  dst = go;  off = i; }
    else if (i < 16777216) { src = u;  dst = uo;  off = i - 8388608; }
    else if (i < 25165824) { src = d;  dst = dd;  off = i - 16777216; }
    else if (i < 26214400) { src = sg; dst = sgo; off = i - 25165824; }
    else if (i < 27262976) { src = su; dst = suo; off = i - 26214400; }
    else if (i < 28311552) { src = sd; dst = sdo; off = i - 27262976; }
    else if (i < 30408704) { src = x;  dst = xo;  off = i - 28311552; }
    else return;
    float4 a = *(const float4*)(src + off);
    float4 b = *(const float4*)(src + off + 4);
    short4 s0 = { f2bf(a.x), f2bf(a.y), f2bf(a.z), f2bf(a.w) };
    short4 s1 = { f2bf(b.x), f2bf(b.y), f2bf(b.z), f2bf(b.w) };
    *(short4*)(dst + off) = s0;
    *(short4*)(dst + off + 4) = s1;
}

// ---------------------------------------------------------------- router (parallel logits)
// 256 threads, 8 tokens/block. Phase 1: logits GEMM in fp32 (exact).
// Phase 2: 8 threads do serial top-k with jax tie semantics (lowest index).
#define RTOK 8
__global__ __launch_bounds__(256)
void router_kernel(const float* __restrict__ x,
                   const float* __restrict__ rw,
                   const float* __restrict__ ebias,
                   int* __restrict__ counts,
                   int* __restrict__ lists,
                   float* __restrict__ lweights) {
    __shared__ float Xs[RTOK][H_DIM + 4];    // pad 1028: stride-1024 bank aliasing killed
    __shared__ float part[256];
    __shared__ float lg[RTOK][E_EXP];
    const int tid = threadIdx.x;
    const int t0 = blockIdx.x * RTOK;

    // stage 8 token rows (coalesced: per-instr the 32-thread row-group reads 512 contiguous floats)
    {
        int r = tid >> 5;
        int cb = (tid & 31) * 4;
        const float* xr = x + (size_t)(t0 + r) * H_DIM;
        #pragma unroll
        for (int j = 0; j < 8; ++j) {
            int c = cb + j * 128;
            *(float4*)&Xs[r][c] = *(const float4*)(xr + c);
        }
    }
    __syncthreads();

    // partial logit: thread = (half, expert, token)
    {
        int half = tid >> 7;
        int e    = (tid >> 3) & 15;
        int tok  = tid & 7;
        const float* wr  = rw + (size_t)e * H_DIM + half * 512;
        const float* xsr = &Xs[tok][half * 512];
        float acc = 0.f;
        #pragma unroll 4
        for (int k = 0; k < 512; k += 4) {
            float4 w = *(const float4*)(wr + k);
            float4 xv = *(const float4*)(xsr + k);
            acc += w.x * xv.x + w.y * xv.y + w.z * xv.z + w.w * xv.w;
        }
        part[tid] = acc;
    }
    __syncthreads();
    if (tid < 128) {
        float logit = part[tid] + part[tid + 128];
        lg[tid & 7][(tid >> 3) & 15] = logit;
    }
    __syncthreads();
    if (tid >= RTOK) return;

    const int t = t0 + tid;
    float scores[E_EXP], sc[E_EXP];
    for (int e = 0; e < E_EXP; ++e) {
        float s = 1.f / (1.f + expf(-lg[tid][e]));
        scores[e] = s;
        sc[e] = s + ebias[e];
    }
    float gs[G_GRP];
    for (int g = 0; g < G_GRP; ++g) {
        float v[4] = { sc[g*4], sc[g*4+1], sc[g*4+2], sc[g*4+3] };
        float b1 = -1e30f; int i1 = -1;
        for (int j = 0; j < 4; ++j) if (v[j] > b1) { b1 = v[j]; i1 = j; }
        float b2 = -1e30f;
        for (int j = 0; j < 4; ++j) if (j != i1 && v[j] > b2) b2 = v[j];
        gs[g] = b1 + b2;
    }
    int g1 = -1; float b1 = -1e30f;
    for (int g = 0; g < G_GRP; ++g) if (gs[g] > b1) { b1 = gs[g]; g1 = g; }
    int g2 = -1; float b2 = -1e30f;
    for (int g = 0; g < G_GRP; ++g) if (g != g1 && gs[g] > b2) { b2 = gs[g]; g2 = g; }

    float masked[E_EXP];
    for (int e = 0; e < E_EXP; ++e) {
        int grp = e >> 2;
        masked[e] = (grp == g1 || grp == g2) ? sc[e] : 0.f;
    }
    int tidx[K_TOP]; float tw[K_TOP];
    for (int k = 0; k < K_TOP; ++k) {
        int bi = -1; float bv = -1e30f;
        for (int e = 0; e < E_EXP; ++e) if (masked[e] > bv) { bv = masked[e]; bi = e; }
        tidx[k] = bi;
        tw[k] = scores[bi];
        masked[bi] = -1e30f;
    }
    float sum = tw[0] + tw[1] + tw[2] + tw[3];
    float inv = SCALE_F / (sum + 1e-20f);
    for (int k = 0; k < K_TOP; ++k) {
        int e = tidx[k];
        int pos = atomicAdd(&counts[e], 1);
        lists[e * T_TOK + pos] = t;
        lweights[e * T_TOK + pos] = tw[k] * inv;
    }
}

// ---------------------------------------------------------------- Kernel A: gate+up+silu -> h (bf16)
// block = 64 tokens x 64 i-cols, K=1024 in 64-chunks through LDS.
// bx < 4096: routed (e=bx>>8, mt=(bx>>3)&31, nt=bx&7); else shared (512 blocks).
__global__ __launch_bounds__(256)
void moe_gateup(const short* __restrict__ Xbf,
                const int* __restrict__ counts, const int* __restrict__ lists,
                const short* __restrict__ gw, const short* __restrict__ uw,
                const short* __restrict__ sgw, const short* __restrict__ suw,
                short* __restrict__ h_r, short* __restrict__ h_sh) {
    __shared__ __align__(16) short Xs[64*64], Gs[64*64], Us[64*64];
    __shared__ int toks[64];
    const int bx = blockIdx.x, tid = threadIdx.x;
    const short *gbase, *ubase; short* hout; int hpitch;
    if (bx < 4096) {
        int e = bx >> 8, mt = (bx >> 3) & 31, nt = bx & 7;
        int cnt = counts[e];
        if (mt * 64 >= cnt) return;
        if (tid < 64) {
            int j = mt * 64 + tid;
            toks[tid] = (j < cnt) ? lists[e * T_TOK + j] : lists[e * T_TOK];
        }
        gbase = gw + (size_t)e * I_SZ * H_DIM + (size_t)(nt * 64) * H_DIM;
        ubase = uw + (size_t)e * I_SZ * H_DIM + (size_t)(nt * 64) * H_DIM;
        hout  = h_r + ((size_t)e * T_TOK + mt * 64) * I_SZ + nt * 64;
        hpitch = I_SZ;
    } else {
        int b2 = bx - 4096, mt = b2 >> 4, nt = b2 & 15;
        if (tid < 64) toks[tid] = mt * 64 + tid;
        gbase = sgw + (size_t)(nt * 64) * H_DIM;
        ubase = suw + (size_t)(nt * 64) * H_DIM;
        hout  = h_sh + (size_t)(mt * 64) * 1024 + nt * 64;
        hpitch = 1024;
    }
    __syncthreads();

    const int lane = tid & 63, wv = tid >> 6;
    const int mw = wv & 1, nw = wv >> 1;
    const int lr = lane & 15, lq = lane >> 4;

    f32x4 accG[2][2], accU[2][2];
    #pragma unroll
    for (int a = 0; a < 2; ++a)
        #pragma unroll
        for (int b = 0; b < 2; ++b) {
            accG[a][b] = (f32x4){0.f,0.f,0.f,0.f};
            accU[a][b] = (f32x4){0.f,0.f,0.f,0.f};
        }

    const int srow = tid >> 2, s2 = tid & 3;
    const short* xrow = Xbf + (size_t)toks[srow] * H_DIM + s2 * 16;
    const short* grow = gbase + (size_t)srow * H_DIM + s2 * 16;
    const short* urow = ubase + (size_t)srow * H_DIM + s2 * 16;
    const int st0 = lds_idx(srow, s2 * 16);
    const int st1 = lds_idx(srow, s2 * 16 + 8);

    for (int kc = 0; kc < H_DIM; kc += 64) {
        short8v xa = *(const short8v*)(xrow + kc);
        short8v xb = *(const short8v*)(xrow + kc + 8);
        short8v ga = *(const short8v*)(grow + kc);
        short8v gb = *(const short8v*)(grow + kc + 8);
        short8v ua = *(const short8v*)(urow + kc);
        short8v ub = *(const short8v*)(urow + kc + 8);
        __syncthreads();
        *(short8v*)&Xs[st0] = xa; *(short8v*)&Xs[st1] = xb;
        *(short8v*)&Gs[st0] = ga; *(short8v*)&Gs[st1] = gb;
        *(short8v*)&Us[st0] = ua; *(short8v*)&Us[st1] = ub;
        __syncthreads();
        #pragma unroll
        for (int kk = 0; kk < 64; kk += 32) {
            const int kf = kk + lq * 8;
            bfrag a0 = *(const bfrag*)&Xs[lds_idx(mw*32 + lr,      kf)];
            bfrag a1 = *(const bfrag*)&Xs[lds_idx(mw*32 + 16 + lr, kf)];
            bfrag g0 = *(const bfrag*)&Gs[lds_idx(nw*32 + lr,      kf)];
            bfrag g1 = *(const bfrag*)&Gs[lds_idx(nw*32 + 16 + lr, kf)];
            bfrag u0 = *(const bfrag*)&Us[lds_idx(nw*32 + lr,      kf)];
            bfrag u1 = *(const bfrag*)&Us[lds_idx(nw*32 + 16 + lr, kf)];
            accG[0][0] = MFMA16(a0, g0, accG[0][0]);
            accG[0][1] = MFMA16(a0, g1, accG[0][1]);
            accG[1][0] = MFMA16(a1, g0, accG[1][0]);
            accG[1][1] = MFMA16(a1, g1, accG[1][1]);
            accU[0][0] = MFMA16(a0, u0, accU[0][0]);
            accU[0][1] = MFMA16(a0, u1, accU[0][1]);
            accU[1][0] = MFMA16(a1, u0, accU[1][0]);
            accU[1][1] = MFMA16(a1, u1, accU[1][1]);
        }
    }

    #pragma unroll
    for (int fm = 0; fm < 2; ++fm)
        #pragma unroll
        for (int fn = 0; fn < 2; ++fn)
            #pragma unroll
            for (int r = 0; r < 4; ++r) {
                int trow = mw*32 + fm*16 + lq*4 + r;
                int col  = nw*32 + fn*16 + lr;
                float g = accG[fm][fn][r], u = accU[fm][fn][r];
                hout[(size_t)trow * hpitch + col] = f2bf(g * u / (1.f + __expf(-g)));
            }
}

// ---------------------------------------------------------------- Kernel B: down-proj
// mode 1 (shared): K=1024, plain store of full output (runs FIRST).
// mode 0 (routed): K=512, atomicAdd scaled by routing weight.
__global__ __launch_bounds__(256)
void moe_down(const short* __restrict__ h_r, const short* __restrict__ h_sh,
              const int* __restrict__ counts, const int* __restrict__ lists,
              const float* __restrict__ lw, const short* __restrict__ dw,
              const short* __restrict__ shdw, float* __restrict__ out, int mode) {
    __shared__ __align__(16) short Hs[64*64], Ws[64*64];
    __shared__ int toks[64];
    __shared__ float tws[64];
    const int bx = blockIdx.x, tid = threadIdx.x;
    const short *abase, *bbase; int apitch, bpitch, K, n0;
    if (mode == 0) {
        int e = bx >> 9, mt = (bx >> 4) & 31, nt = bx & 15;
        int cnt = counts[e];
        if (mt * 64 >= cnt) return;
        if (tid < 64) {
            int j = mt * 64 + tid;
            toks[tid] = (j < cnt) ? lists[e * T_TOK + j] : 0;
            tws[tid]  = (j < cnt) ? lw[e * T_TOK + j] : 0.f;
        }
        abase = h_r + ((size_t)e * T_TOK + mt * 64) * I_SZ;
        bbase = dw + (size_t)e * H_DIM * I_SZ + (size_t)(nt * 64) * I_SZ;
        apitch = I_SZ; bpitch = I_SZ; K = I_SZ; n0 = nt * 64;
    } else {
        int mt = bx >> 4, nt = bx & 15;
        if (tid < 64) { toks[tid] = mt * 64 + tid; tws[tid] = 1.f; }
        abase = h_sh + (size_t)(mt * 64) * 1024;
        bbase = shdw + (size_t)(nt * 64) * 1024;
        apitch = 1024; bpitch = 1024; K = 1024; n0 = nt * 64;
    }
    __syncthreads();

    const int lane = tid & 63, wv = tid >> 6;
    const int mw = wv & 1, nw = wv >> 1;
    const int lr = lane & 15, lq = lane >> 4;

    f32x4 acc[2][2];
    #pragma unroll
    for (int a = 0; a < 2; ++a)
        #pragma unroll
        for (int b = 0; b < 2; ++b) acc[a][b] = (f32x4){0.f,0.f,0.f,0.f};

    const int srow = tid >> 2, s2 = tid & 3;
    const short* arow = abase + (size_t)srow * apitch + s2 * 16;
    const short* brow = bbase + (size_t)srow * bpitch + s2 * 16;
    const int st0 = lds_idx(srow, s2 * 16);
    const int st1 = lds_idx(srow, s2 * 16 + 8);

    for (int kc = 0; kc < K; kc += 64) {
        short8v ha = *(const short8v*)(arow + kc);
        short8v hb = *(const short8v*)(arow + kc + 8);
        short8v wa = *(const short8v*)(brow + kc);
        short8v wb = *(const short8v*)(brow + kc + 8);
        __syncthreads();
        *(short8v*)&Hs[st0] = ha; *(short8v*)&Hs[st1] = hb;
        *(short8v*)&Ws[st0] = wa; *(short8v*)&Ws[st1] = wb;
        __syncthreads();
        #pragma unroll
        for (int kk = 0; kk < 64; kk += 32) {
            const int kf = kk + lq * 8;
            bfrag a0 = *(const bfrag*)&Hs[lds_idx(mw*32 + lr,      kf)];
            bfrag a1 = *(const bfrag*)&Hs[lds_idx(mw*32 + 16 + lr, kf)];
            bfrag b0 = *(const bfrag*)&Ws[lds_idx(nw*32 + lr,      kf)];
            bfrag b1 = *(const bfrag*)&Ws[lds_idx(nw*32 + 16 + lr, kf)];
            acc[0][0] = MFMA16(a0, b0, acc[0][0]);
            acc[0][1] = MFMA16(a0, b1, acc[0][1]);
            acc[1][0] = MFMA16(a1, b0, acc[1][0]);
            acc[1][1] = MFMA16(a1, b1, acc[1][1]);
        }
    }

    #pragma unroll
    for (int fm = 0; fm < 2; ++fm)
        #pragma unroll
        for (int fn = 0; fn < 2; ++fn)
            #pragma unroll
            for (int r = 0; r < 4; ++r) {
                int trow = mw*32 + fm*16 + lq*4 + r;
                int col  = n0 + nw*32 + fn*16 + lr;
                float v = acc[fm][fn][r];
                if (mode == 0) {
                    float w = tws[trow];
                    if (w != 0.f)
                        atomicAdd(out + (size_t)toks[trow] * H_DIM + col, v * w);
                } else {
                    out[(size_t)toks[trow] * H_DIM + col] = v;
                }
            }
}

// ---------------------------------------------------------------- fallback (fused, fp32 weights)
__global__ void zero_kernel(float* __restrict__ out, int n4, int* __restrict__ counts) {
    int i = blockIdx.x * blockDim.x + threadIdx.x;
    if (i < n4) {
        float4 z = {0.f, 0.f, 0.f, 0.f};
        *(float4*)(out + (size_t)i * 4) = z;
    }
    if (blockIdx.x == 0 && threadIdx.x < E_EXP) counts[threadIdx.x] = 0;
}

__device__ __forceinline__ bfrag load_wfrag_f(const float* p) {
    float4 a = *(const float4*)(p);
    float4 b = *(const float4*)(p + 4);
    bfrag r;
    r[0]=f2bf(a.x); r[1]=f2bf(a.y); r[2]=f2bf(a.z); r[3]=f2bf(a.w);
    r[4]=f2bf(b.x); r[5]=f2bf(b.y); r[6]=f2bf(b.z); r[7]=f2bf(b.w);
    return r;
}

#define TM 32
__global__ __launch_bounds__(256)
void moe_gemm_fb(const float* __restrict__ x,
                 const float* __restrict__ gate_w, const float* __restrict__ up_w,
                 const float* __restrict__ down_w, const float* __restrict__ sh_gate,
                 const float* __restrict__ sh_up, const float* __restrict__ sh_down,
                 const int* __restrict__ counts, const int* __restrict__ lists,
                 const float* __restrict__ lweights, float* __restrict__ out) {
    const int bx = blockIdx.x;
    const int e = bx >> 6;
    const int tile = bx & 63;
    int ntok; const float *gp, *upp, *dpp; int dpitch;
    if (e < E_EXP) {
        ntok = counts[e];
        gp  = gate_w + (size_t)e * I_SZ * H_DIM;
        upp = up_w   + (size_t)e * I_SZ * H_DIM;
        dpp = down_w + (size_t)e * H_DIM * I_SZ;
        dpitch = I_SZ;
    } else {
        int s = e - E_EXP;
        ntok = T_TOK;
        gp  = sh_gate + (size_t)s * I_SZ * H_DIM;
        upp = sh_up   + (size_t)s * I_SZ * H_DIM;
        dpp = sh_down + (size_t)s * I_SZ;
        dpitch = 2 * I_SZ;
    }
    const int start = tile * TM;
    if (start >= ntok) return;

    __shared__ __align__(16) short Xs2[TM][H_DIM + 8];
    __shared__ __align__(16) short Hs2[TM][I_SZ + 8];
    __shared__ int   toks[TM];
    __shared__ float tws[TM];

    const int tid = threadIdx.x;
    if (tid < TM) {
        int j = start + tid;
        int tok = 0; float w = 0.f;
        if (j < ntok) {
            if (e < E_EXP) { tok = lists[e * T_TOK + j]; w = lweights[e * T_TOK + j]; }
            else           { tok = j;                    w = 1.0f; }
        }
        toks[tid] = tok; tws[tid] = w;
    }
    __syncthreads();
    {
        int r = tid >> 3;
        int c0 = (tid & 7) * 128;
        const float* xr = x + (size_t)toks[r] * H_DIM + c0;
        #pragma unroll
        for (int c = 0; c < 128; c += 4) {
            float4 v = *(const float4*)(xr + c);
            short4 s = { f2bf(v.x), f2bf(v.y), f2bf(v.z), f2bf(v.w) };
            *(short4*)&Xs2[r][c0 + c] = s;
        }
    }
    __syncthreads();

    const int lane = tid & 63;
    const int wv   = tid >> 6;
    const int lr   = lane & 15;
    const int lq   = lane >> 4;
    const int ko   = lq * 8;

    for (int it = 0; it < I_SZ / 64; ++it) {
        const int i0 = wv * (I_SZ / 4) + it * 16;
        const float* grow = gp  + (size_t)(i0 + lr) * H_DIM;
        const float* urow = upp + (size_t)(i0 + lr) * H_DIM;
        f32x4 aG0 = {0.f,0.f,0.f,0.f}, aU0 = {0.f,0.f,0.f,0.f};
        f32x4 aG1 = {0.f,0.f,0.f,0.f}, aU1 = {0.f,0.f,0.f,0.f};
        for (int k0 = 0; k0 < H_DIM; k0 += 32) {
            bfrag bg = load_wfrag_f(grow + k0 + ko);
            bfrag bu = load_wfrag_f(urow + k0 + ko);
            bfrag a0 = *(const bfrag*)&Xs2[lr][k0 + ko];
            bfrag a1 = *(const bfrag*)&Xs2[lr + 16][k0 + ko];
            aG0 = MFMA16(a0, bg, aG0);
            aG1 = MFMA16(a1, bg, aG1);
            aU0 = MFMA16(a0, bu, aU0);
            aU1 = MFMA16(a1, bu, aU1);
        }
        #pragma unroll
        for (int r = 0; r < 4; ++r) {
            const int trow = lq * 4 + r;
            float g0 = aG0[r], u0 = aU0[r];
            Hs2[trow][i0 + lr] = f2bf(g0 * u0 / (1.f + __expf(-g0)));
            float g1 = aG1[r], u1 = aU1[r];
            Hs2[trow + 16][i0 + lr] = f2bf(g1 * u1 / (1.f + __expf(-g1)));
        }
    }
    __syncthreads();

    for (int ct = 0; ct < H_DIM / 64; ++ct) {
        const int c0 = wv * (H_DIM / 4) + ct * 16;
        const float* drow = dpp + (size_t)(c0 + lr) * dpitch;
        f32x4 a0 = {0.f,0.f,0.f,0.f}, a1 = {0.f,0.f,0.f,0.f};
        for (int k0 = 0; k0 < I_SZ; k0 += 32) {
            bfrag bd = load_wfrag_f(drow + k0 + ko);
            bfrag h0 = *(const bfrag*)&Hs2[lr][k0 + ko];
            bfrag h1 = *(const bfrag*)&Hs2[lr + 16][k0 + ko];
            a0 = MFMA16(h0, bd, a0);
            a1 = MFMA16(h1, bd, a1);
        }
        #pragma unroll
        for (int r = 0; r < 4; ++r) {
            const int trow = lq * 4 + r;
            float w0 = tws[trow], w1 = tws[trow + 16];
            if (w0 != 0.f) atomicAdd(out + (size_t)toks[trow] * H_DIM + c0 + lr, a0[r] * w0);
            if (w1 != 0.f) atomicAdd(out + (size_t)toks[trow + 16] * H_DIM + c0 + lr, a1[r] * w1);
        }
    }
}

// ---------------------------------------------------------------- launch
extern "C" void kernel_launch(void* const* d_in, const int* in_sizes, int n_in,
                              void* d_out, int out_size, void* d_ws, size_t ws_size,
                              hipStream_t stream) {
    const float* x     = (const float*)d_in[0];
    const float* rw    = (const float*)d_in[1];
    const float* ebias = (const float*)d_in[2];
    const float* gate_w = (const float*)d_in[3];
    const float* up_w   = (const float*)d_in[4];
    const float* down_w = (const float*)d_in[5];
    const float* shg    = (const float*)d_in[6];
    const float* shu    = (const float*)d_in[7];
    const float* shd    = (const float*)d_in[8];
    float* out = (float*)d_out;

    char* ws = (char*)d_ws;
    int*   counts = (int*)ws;                       // 64 B used
    int*   lists  = (int*)(ws + 1024);              // 16*2048 ints  = 128 KB
    float* lw     = (float*)(ws + 1024 + 131072);   // 16*2048 float = 128 KB
    size_t off = 1024 + 131072 + 131072;            // 263168

    const size_t n_gu = (size_t)E_EXP * I_SZ * H_DIM;   // 8388608
    const size_t n_sh = (size_t)H_DIM * 1024;           // 1048576
    const size_t n_x  = (size_t)T_TOK * H_DIM;          // 2097152

    short* g_bf  = (short*)(ws + off); off += n_gu * 2;
    short* u_bf  = (short*)(ws + off); off += n_gu * 2;
    short* d_bf  = (short*)(ws + off); off += n_gu * 2;
    short* sg_bf = (short*)(ws + off); off += n_sh * 2;
    short* su_bf = (short*)(ws + off); off += n_sh * 2;
    short* sd_bf = (short*)(ws + off); off += n_sh * 2;
    short* x_bf  = (short*)(ws + off); off += n_x * 2;
    short* h_r   = (short*)(ws + off); off += (size_t)E_EXP * T_TOK * I_SZ * 2;  // 32 MB
    short* h_sh  = (short*)(ws + off); off += (size_t)T_TOK * 1024 * 2;          // 4 MB
    const size_t need = off;

    if (ws_size >= need) {
        hipMemsetAsync(counts, 0, 64, stream);
        convert_all<<<14848, 256, 0, stream>>>(gate_w, up_w, down_w, shg, shu, shd, x,
                                               g_bf, u_bf, d_bf, sg_bf, su_bf, sd_bf, x_bf);
        router_kernel<<<T_TOK / RTOK, 256, 0, stream>>>(x, rw, ebias, counts, lists, lw);
        moe_gateup<<<4096 + 512, 256, 0, stream>>>(x_bf, counts, lists, g_bf, u_bf,
                                                   sg_bf, su_bf, h_r, h_sh);
        // shared first (plain store initializes out), then routed (atomicAdd)
        moe_down<<<512, 256, 0, stream>>>(h_r, h_sh, counts, lists, lw, d_bf, sd_bf, out, 1);
        moe_down<<<8192, 256, 0, stream>>>(h_r, h_sh, counts, lists, lw, d_bf, sd_bf, out, 0);
    } else {
        zero_kernel<<<(out_size / 4 + 255) / 256, 256, 0, stream>>>(out, out_size / 4, counts);
        router_kernel<<<T_TOK / RTOK, 256, 0, stream>>>(x, rw, ebias, counts, lists, lw);
        moe_gemm_fb<<<(E_EXP + 2) * 64, 256, 0, stream>>>(x, gate_w, up_w, down_w,
                                                          shg, shu, shd, counts, lists, lw, out);
    }
}

// Round 4
// 279.268 us; speedup vs baseline: 2.3797x; 1.0383x over previous
//
#include <hip/hip_runtime.h>
#include <hip/hip_bf16.h>
#include <math.h>

// Problem constants (DeepseekV3MoE reference)
#define T_TOK 2048
#define H_DIM 1024
#define E_EXP 16
#define K_TOP 4
#define G_GRP 4
#define I_SZ 512
#define SCALE_F 2.5f

typedef __attribute__((ext_vector_type(8))) short bfrag;    // 8 bf16 (4 VGPR)
typedef __attribute__((ext_vector_type(8))) short short8v;
typedef __attribute__((ext_vector_type(4))) float f32x4;    // MFMA acc

#define MFMA16(a, b, c) __builtin_amdgcn_mfma_f32_16x16x32_bf16(a, b, c, 0, 0, 0)

__device__ __forceinline__ short f2bf(float f) {
    union { float f; unsigned u; } v; v.f = f;
    unsigned u = v.u;
    u += 0x7fffu + ((u >> 16) & 1u);   // RNE
    return (short)(u >> 16);
}

// XOR-swizzled LDS index for 64-short rows: 8 segments of 8 shorts (16 B),
// physical segment = logical_seg ^ (row & 7).  Conflict-free for ds_read_b128
// fragment reads (verified: SQ_LDS_BANK_CONFLICT == 0).
__device__ __forceinline__ int lds_idx(int row, int k) {
    return row * 64 + ((((k >> 3) ^ (row & 7))) << 3) + (k & 7);
}

// global -> LDS direct DMA, 16 B per lane. LDS dest = wave-uniform base +
// lane*16 (m104/m108), so the XOR swizzle is applied on the GLOBAL source
// offset instead (lane reads logical seg (l&7)^(l>>3) of its row).
typedef __attribute__((address_space(1))) unsigned int as1_u32;
typedef __attribute__((address_space(3))) unsigned int as3_u32;
__device__ __forceinline__ void gld16(const short* g, short* l) {
    __builtin_amdgcn_global_load_lds((const as1_u32*)g, (as3_u32*)l, 16, 0, 0);
}

// ---------------------------------------------------------------- fused fp32->bf16 convert
__global__ __launch_bounds__(256) void convert_all(
        const float* __restrict__ g, const float* __restrict__ u, const float* __restrict__ d,
        const float* __restrict__ sg, const float* __restrict__ su, const float* __restrict__ sd,
        const float* __restrict__ x,
        short* __restrict__ go, short* __restrict__ uo, short* __restrict__ dd,
        short* __restrict__ sgo, short* __restrict__ suo, short* __restrict__ sdo,
        short* __restrict__ xo) {
    long i = ((long)blockIdx.x * 256 + threadIdx.x) * 8;
    const float* src; short* dst; long off;
    if      (i < 8388608)  { src = g;  dst = go;  off = i; }
    else if (i < 16777216) { src = u;  dst = uo;  off = i - 8388608; }
    else if (i < 25165824) { src = d;  dst = dd;  off = i - 16777216; }
    else if (i < 26214400) { src = sg; dst = sgo; off = i - 25165824; }
    else if (i < 27262976) { src = su; dst = suo; off = i - 26214400; }
    else if (i < 28311552) { src = sd; dst = sdo; off = i - 27262976; }
    else if (i < 30408704) { src = x;  dst = xo;  off = i - 28311552; }
    else return;
    float4 a = *(const float4*)(src + off);
    float4 b = *(const float4*)(src + off + 4);
    short4 s0 = { f2bf(a.x), f2bf(a.y), f2bf(a.z), f2bf(a.w) };
    short4 s1 = { f2bf(b.x), f2bf(b.y), f2bf(b.z), f2bf(b.w) };
    *(short4*)(dst + off) = s0;
    *(short4*)(dst + off + 4) = s1;
}

// ---------------------------------------------------------------- router (parallel logits)
#define RTOK 8
__global__ __launch_bounds__(256)
void router_kernel(const float* __restrict__ x,
                   const float* __restrict__ rw,
                   const float* __restrict__ ebias,
                   int* __restrict__ counts,
                   int* __restrict__ lists,
                   float* __restrict__ lweights) {
    __shared__ float Xs[RTOK][H_DIM + 4];
    __shared__ float part[256];
    __shared__ float lg[RTOK][E_EXP];
    const int tid = threadIdx.x;
    const int t0 = blockIdx.x * RTOK;

    {
        int r = tid >> 5;
        int cb = (tid & 31) * 4;
        const float* xr = x + (size_t)(t0 + r) * H_DIM;
        #pragma unroll
        for (int j = 0; j < 8; ++j) {
            int c = cb + j * 128;
            *(float4*)&Xs[r][c] = *(const float4*)(xr + c);
        }
    }
    __syncthreads();

    {
        int half = tid >> 7;
        int e    = (tid >> 3) & 15;
        int tok  = tid & 7;
        const float* wr  = rw + (size_t)e * H_DIM + half * 512;
        const float* xsr = &Xs[tok][half * 512];
        float acc = 0.f;
        #pragma unroll 4
        for (int k = 0; k < 512; k += 4) {
            float4 w = *(const float4*)(wr + k);
            float4 xv = *(const float4*)(xsr + k);
            acc += w.x * xv.x + w.y * xv.y + w.z * xv.z + w.w * xv.w;
        }
        part[tid] = acc;
    }
    __syncthreads();
    if (tid < 128) {
        float logit = part[tid] + part[tid + 128];
        lg[tid & 7][(tid >> 3) & 15] = logit;
    }
    __syncthreads();
    if (tid >= RTOK) return;

    const int t = t0 + tid;
    float scores[E_EXP], sc[E_EXP];
    for (int e = 0; e < E_EXP; ++e) {
        float s = 1.f / (1.f + expf(-lg[tid][e]));
        scores[e] = s;
        sc[e] = s + ebias[e];
    }
    float gs[G_GRP];
    for (int g = 0; g < G_GRP; ++g) {
        float v[4] = { sc[g*4], sc[g*4+1], sc[g*4+2], sc[g*4+3] };
        float b1 = -1e30f; int i1 = -1;
        for (int j = 0; j < 4; ++j) if (v[j] > b1) { b1 = v[j]; i1 = j; }
        float b2 = -1e30f;
        for (int j = 0; j < 4; ++j) if (j != i1 && v[j] > b2) b2 = v[j];
        gs[g] = b1 + b2;
    }
    int g1 = -1; float b1 = -1e30f;
    for (int g = 0; g < G_GRP; ++g) if (gs[g] > b1) { b1 = gs[g]; g1 = g; }
    int g2 = -1; float b2 = -1e30f;
    for (int g = 0; g < G_GRP; ++g) if (g != g1 && gs[g] > b2) { b2 = gs[g]; g2 = g; }

    float masked[E_EXP];
    for (int e = 0; e < E_EXP; ++e) {
        int grp = e >> 2;
        masked[e] = (grp == g1 || grp == g2) ? sc[e] : 0.f;
    }
    int tidx[K_TOP]; float tw[K_TOP];
    for (int k = 0; k < K_TOP; ++k) {
        int bi = -1; float bv = -1e30f;
        for (int e = 0; e < E_EXP; ++e) if (masked[e] > bv) { bv = masked[e]; bi = e; }
        tidx[k] = bi;
        tw[k] = scores[bi];
        masked[bi] = -1e30f;
    }
    float sum = tw[0] + tw[1] + tw[2] + tw[3];
    float inv = SCALE_F / (sum + 1e-20f);
    for (int k = 0; k < K_TOP; ++k) {
        int e = tidx[k];
        int pos = atomicAdd(&counts[e], 1);
        lists[e * T_TOK + pos] = t;
        lweights[e * T_TOK + pos] = tw[k] * inv;
    }
}

// ---------------------------------------------------------------- Kernel A: gate+up+silu -> h
// block = 64 tokens x 64 i-cols, K=1024, global_load_lds(16B) staging.
__global__ __launch_bounds__(256)
void moe_gateup(const short* __restrict__ Xbf,
                const int* __restrict__ counts, const int* __restrict__ lists,
                const short* __restrict__ gw, const short* __restrict__ uw,
                const short* __restrict__ sgw, const short* __restrict__ suw,
                short* __restrict__ h_r, short* __restrict__ h_sh) {
    __shared__ __align__(16) short Xs[64*64], Gs[64*64], Us[64*64];   // 24 KB
    __shared__ int toks[64];
    const int bx = blockIdx.x, tid = threadIdx.x;
    const short *gbase, *ubase; short* hout; int hpitch;
    if (bx < 4096) {
        int e = bx >> 8, mt = (bx >> 3) & 31, nt = bx & 7;
        int cnt = counts[e];
        if (mt * 64 >= cnt) return;
        if (tid < 64) {
            int j = mt * 64 + tid;
            toks[tid] = (j < cnt) ? lists[e * T_TOK + j] : lists[e * T_TOK];
        }
        gbase = gw + (size_t)e * I_SZ * H_DIM + (size_t)(nt * 64) * H_DIM;
        ubase = uw + (size_t)e * I_SZ * H_DIM + (size_t)(nt * 64) * H_DIM;
        hout  = h_r + ((size_t)e * T_TOK + mt * 64) * I_SZ + nt * 64;
        hpitch = I_SZ;
    } else {
        int b2 = bx - 4096, mt = b2 >> 4, nt = b2 & 15;
        if (tid < 64) toks[tid] = mt * 64 + tid;
        gbase = sgw + (size_t)(nt * 64) * H_DIM;
        ubase = suw + (size_t)(nt * 64) * H_DIM;
        hout  = h_sh + (size_t)(mt * 64) * 1024 + nt * 64;
        hpitch = 1024;
    }
    __syncthreads();

    const int lane = tid & 63, wv = tid >> 6;
    const int mw = wv & 1, nw = wv >> 1;
    const int lr = lane & 15, lq = lane >> 4;
    const int l3 = lane >> 3, l7 = lane & 7;
    const int seg = (l7 ^ l3) * 8;            // swizzled source seg (shorts)

    // staging: wave wv covers rows [wv*16, wv*16+16) as two 8-row slabs
    const int rowA = wv * 16 + l3, rowB = rowA + 8;
    const short* xA = Xbf   + (size_t)toks[rowA] * H_DIM + seg;
    const short* xB = Xbf   + (size_t)toks[rowB] * H_DIM + seg;
    const short* gA = gbase + (size_t)rowA * H_DIM + seg;
    const short* gB = gbase + (size_t)rowB * H_DIM + seg;
    const short* uA = ubase + (size_t)rowA * H_DIM + seg;
    const short* uB = ubase + (size_t)rowB * H_DIM + seg;
    short* ldsXA = &Xs[(wv*16    ) * 64]; short* ldsXB = &Xs[(wv*16 + 8) * 64];
    short* ldsGA = &Gs[(wv*16    ) * 64]; short* ldsGB = &Gs[(wv*16 + 8) * 64];
    short* ldsUA = &Us[(wv*16    ) * 64]; short* ldsUB = &Us[(wv*16 + 8) * 64];

    f32x4 accG[2][2], accU[2][2];
    #pragma unroll
    for (int a = 0; a < 2; ++a)
        #pragma unroll
        for (int b = 0; b < 2; ++b) {
            accG[a][b] = (f32x4){0.f,0.f,0.f,0.f};
            accU[a][b] = (f32x4){0.f,0.f,0.f,0.f};
        }

    #pragma unroll
    for (int c = 0; c < 16; ++c) {
        const int kc = c * 64;
        gld16(xA + kc, ldsXA); gld16(xB + kc, ldsXB);
        gld16(gA + kc, ldsGA); gld16(gB + kc, ldsGB);
        gld16(uA + kc, ldsUA); gld16(uB + kc, ldsUB);
        __syncthreads();
        #pragma unroll
        for (int kk = 0; kk < 64; kk += 32) {
            const int kf = kk + lq * 8;
            bfrag a0 = *(const bfrag*)&Xs[lds_idx(mw*32 + lr,      kf)];
            bfrag a1 = *(const bfrag*)&Xs[lds_idx(mw*32 + 16 + lr, kf)];
            bfrag g0 = *(const bfrag*)&Gs[lds_idx(nw*32 + lr,      kf)];
            bfrag g1 = *(const bfrag*)&Gs[lds_idx(nw*32 + 16 + lr, kf)];
            bfrag u0 = *(const bfrag*)&Us[lds_idx(nw*32 + lr,      kf)];
            bfrag u1 = *(const bfrag*)&Us[lds_idx(nw*32 + 16 + lr, kf)];
            accG[0][0] = MFMA16(a0, g0, accG[0][0]);
            accG[0][1] = MFMA16(a0, g1, accG[0][1]);
            accG[1][0] = MFMA16(a1, g0, accG[1][0]);
            accG[1][1] = MFMA16(a1, g1, accG[1][1]);
            accU[0][0] = MFMA16(a0, u0, accU[0][0]);
            accU[0][1] = MFMA16(a0, u1, accU[0][1]);
            accU[1][0] = MFMA16(a1, u0, accU[1][0]);
            accU[1][1] = MFMA16(a1, u1, accU[1][1]);
        }
        __syncthreads();
    }

    #pragma unroll
    for (int fm = 0; fm < 2; ++fm)
        #pragma unroll
        for (int fn = 0; fn < 2; ++fn)
            #pragma unroll
            for (int r = 0; r < 4; ++r) {
                int trow = mw*32 + fm*16 + lq*4 + r;
                int col  = nw*32 + fn*16 + lr;
                float g = accG[fm][fn][r], u = accU[fm][fn][r];
                hout[(size_t)trow * hpitch + col] = f2bf(g * u / (1.f + __expf(-g)));
            }
}

// ---------------------------------------------------------------- Kernel B: down-proj (merged)
// bx < 8192: routed (K=512, weighted atomicAdd); else shared (K=1024, atomicAdd, w=1).
// out must be pre-zeroed.
__global__ __launch_bounds__(256)
void moe_down(const short* __restrict__ h_r, const short* __restrict__ h_sh,
              const int* __restrict__ counts, const int* __restrict__ lists,
              const float* __restrict__ lw, const short* __restrict__ dw,
              const short* __restrict__ shdw, float* __restrict__ out) {
    __shared__ __align__(16) short Hs[64*64], Ws[64*64];   // 16 KB
    __shared__ int toks[64];
    __shared__ float tws[64];
    const int bx = blockIdx.x, tid = threadIdx.x;
    const short *abase, *bbase; int apitch, K, n0;
    if (bx < 8192) {
        int e = bx >> 9, mt = (bx >> 4) & 31, nt = bx & 15;
        int cnt = counts[e];
        if (mt * 64 >= cnt) return;
        if (tid < 64) {
            int j = mt * 64 + tid;
            toks[tid] = (j < cnt) ? lists[e * T_TOK + j] : 0;
            tws[tid]  = (j < cnt) ? lw[e * T_TOK + j] : 0.f;
        }
        abase = h_r + ((size_t)e * T_TOK + mt * 64) * I_SZ;
        bbase = dw + (size_t)e * H_DIM * I_SZ + (size_t)(nt * 64) * I_SZ;
        apitch = I_SZ; K = I_SZ; n0 = nt * 64;
    } else {
        int b2 = bx - 8192, mt = b2 >> 4, nt = b2 & 15;
        if (tid < 64) { toks[tid] = mt * 64 + tid; tws[tid] = 1.f; }
        abase = h_sh + (size_t)(mt * 64) * 1024;
        bbase = shdw + (size_t)(nt * 64) * 1024;
        apitch = 1024; K = 1024; n0 = nt * 64;
    }
    __syncthreads();

    const int lane = tid & 63, wv = tid >> 6;
    const int mw = wv & 1, nw = wv >> 1;
    const int lr = lane & 15, lq = lane >> 4;
    const int l3 = lane >> 3, l7 = lane & 7;
    const int seg = (l7 ^ l3) * 8;

    const int rowA = wv * 16 + l3, rowB = rowA + 8;
    const short* aA = abase + (size_t)rowA * apitch + seg;
    const short* aB = abase + (size_t)rowB * apitch + seg;
    const short* bA = bbase + (size_t)rowA * apitch + seg;   // bpitch == apitch (== K)
    const short* bB = bbase + (size_t)rowB * apitch + seg;
    short* ldsHA = &Hs[(wv*16    ) * 64]; short* ldsHB = &Hs[(wv*16 + 8) * 64];
    short* ldsWA = &Ws[(wv*16    ) * 64]; short* ldsWB = &Ws[(wv*16 + 8) * 64];

    f32x4 acc[2][2];
    #pragma unroll
    for (int a = 0; a < 2; ++a)
        #pragma unroll
        for (int b = 0; b < 2; ++b) acc[a][b] = (f32x4){0.f,0.f,0.f,0.f};

    auto chunk = [&](int kc) {
        gld16(aA + kc, ldsHA); gld16(aB + kc, ldsHB);
        gld16(bA + kc, ldsWA); gld16(bB + kc, ldsWB);
        __syncthreads();
        #pragma unroll
        for (int kk = 0; kk < 64; kk += 32) {
            const int kf = kk + lq * 8;
            bfrag a0 = *(const bfrag*)&Hs[lds_idx(mw*32 + lr,      kf)];
            bfrag a1 = *(const bfrag*)&Hs[lds_idx(mw*32 + 16 + lr, kf)];
            bfrag b0 = *(const bfrag*)&Ws[lds_idx(nw*32 + lr,      kf)];
            bfrag b1 = *(const bfrag*)&Ws[lds_idx(nw*32 + 16 + lr, kf)];
            acc[0][0] = MFMA16(a0, b0, acc[0][0]);
            acc[0][1] = MFMA16(a0, b1, acc[0][1]);
            acc[1][0] = MFMA16(a1, b0, acc[1][0]);
            acc[1][1] = MFMA16(a1, b1, acc[1][1]);
        }
        __syncthreads();
    };
    #pragma unroll
    for (int c = 0; c < 8; ++c) chunk(c * 64);
    if (K == 1024) {
        #pragma unroll
        for (int c = 8; c < 16; ++c) chunk(c * 64);
    }

    #pragma unroll
    for (int fm = 0; fm < 2; ++fm)
        #pragma unroll
        for (int fn = 0; fn < 2; ++fn)
            #pragma unroll
            for (int r = 0; r < 4; ++r) {
                int trow = mw*32 + fm*16 + lq*4 + r;
                int col  = n0 + nw*32 + fn*16 + lr;
                float w = tws[trow];
                if (w != 0.f)
                    atomicAdd(out + (size_t)toks[trow] * H_DIM + col, acc[fm][fn][r] * w);
            }
}

// ---------------------------------------------------------------- fallback (fused, fp32 weights)
__global__ void zero_kernel(float* __restrict__ out, int n4, int* __restrict__ counts) {
    int i = blockIdx.x * blockDim.x + threadIdx.x;
    if (i < n4) {
        float4 z = {0.f, 0.f, 0.f, 0.f};
        *(float4*)(out + (size_t)i * 4) = z;
    }
    if (blockIdx.x == 0 && threadIdx.x < E_EXP) counts[threadIdx.x] = 0;
}

__device__ __forceinline__ bfrag load_wfrag_f(const float* p) {
    float4 a = *(const float4*)(p);
    float4 b = *(const float4*)(p + 4);
    bfrag r;
    r[0]=f2bf(a.x); r[1]=f2bf(a.y); r[2]=f2bf(a.z); r[3]=f2bf(a.w);
    r[4]=f2bf(b.x); r[5]=f2bf(b.y); r[6]=f2bf(b.z); r[7]=f2bf(b.w);
    return r;
}

#define TM 32
__global__ __launch_bounds__(256)
void moe_gemm_fb(const float* __restrict__ x,
                 const float* __restrict__ gate_w, const float* __restrict__ up_w,
                 const float* __restrict__ down_w, const float* __restrict__ sh_gate,
                 const float* __restrict__ sh_up, const float* __restrict__ sh_down,
                 const int* __restrict__ counts, const int* __restrict__ lists,
                 const float* __restrict__ lweights, float* __restrict__ out) {
    const int bx = blockIdx.x;
    const int e = bx >> 6;
    const int tile = bx & 63;
    int ntok; const float *gp, *upp, *dpp; int dpitch;
    if (e < E_EXP) {
        ntok = counts[e];
        gp  = gate_w + (size_t)e * I_SZ * H_DIM;
        upp = up_w   + (size_t)e * I_SZ * H_DIM;
        dpp = down_w + (size_t)e * H_DIM * I_SZ;
        dpitch = I_SZ;
    } else {
        int s = e - E_EXP;
        ntok = T_TOK;
        gp  = sh_gate + (size_t)s * I_SZ * H_DIM;
        upp = sh_up   + (size_t)s * I_SZ * H_DIM;
        dpp = sh_down + (size_t)s * I_SZ;
        dpitch = 2 * I_SZ;
    }
    const int start = tile * TM;
    if (start >= ntok) return;

    __shared__ __align__(16) short Xs2[TM][H_DIM + 8];
    __shared__ __align__(16) short Hs2[TM][I_SZ + 8];
    __shared__ int   toks[TM];
    __shared__ float tws[TM];

    const int tid = threadIdx.x;
    if (tid < TM) {
        int j = start + tid;
        int tok = 0; float w = 0.f;
        if (j < ntok) {
            if (e < E_EXP) { tok = lists[e * T_TOK + j]; w = lweights[e * T_TOK + j]; }
            else           { tok = j;                    w = 1.0f; }
        }
        toks[tid] = tok; tws[tid] = w;
    }
    __syncthreads();
    {
        int r = tid >> 3;
        int c0 = (tid & 7) * 128;
        const float* xr = x + (size_t)toks[r] * H_DIM + c0;
        #pragma unroll
        for (int c = 0; c < 128; c += 4) {
            float4 v = *(const float4*)(xr + c);
            short4 s = { f2bf(v.x), f2bf(v.y), f2bf(v.z), f2bf(v.w) };
            *(short4*)&Xs2[r][c0 + c] = s;
        }
    }
    __syncthreads();

    const int lane = tid & 63;
    const int wv   = tid >> 6;
    const int lr   = lane & 15;
    const int lq   = lane >> 4;
    const int ko   = lq * 8;

    for (int it = 0; it < I_SZ / 64; ++it) {
        const int i0 = wv * (I_SZ / 4) + it * 16;
        const float* grow = gp  + (size_t)(i0 + lr) * H_DIM;
        const float* urow = upp + (size_t)(i0 + lr) * H_DIM;
        f32x4 aG0 = {0.f,0.f,0.f,0.f}, aU0 = {0.f,0.f,0.f,0.f};
        f32x4 aG1 = {0.f,0.f,0.f,0.f}, aU1 = {0.f,0.f,0.f,0.f};
        for (int k0 = 0; k0 < H_DIM; k0 += 32) {
            bfrag bg = load_wfrag_f(grow + k0 + ko);
            bfrag bu = load_wfrag_f(urow + k0 + ko);
            bfrag a0 = *(const bfrag*)&Xs2[lr][k0 + ko];
            bfrag a1 = *(const bfrag*)&Xs2[lr + 16][k0 + ko];
            aG0 = MFMA16(a0, bg, aG0);
            aG1 = MFMA16(a1, bg, aG1);
            aU0 = MFMA16(a0, bu, aU0);
            aU1 = MFMA16(a1, bu, aU1);
        }
        #pragma unroll
        for (int r = 0; r < 4; ++r) {
            const int trow = lq * 4 + r;
            float g0 = aG0[r], u0 = aU0[r];
            Hs2[trow][i0 + lr] = f2bf(g0 * u0 / (1.f + __expf(-g0)));
            float g1 = aG1[r], u1 = aU1[r];
            Hs2[trow + 16][i0 + lr] = f2bf(g1 * u1 / (1.f + __expf(-g1)));
        }
    }
    __syncthreads();

    for (int ct = 0; ct < H_DIM / 64; ++ct) {
        const int c0 = wv * (H_DIM / 4) + ct * 16;
        const float* drow = dpp + (size_t)(c0 + lr) * dpitch;
        f32x4 a0 = {0.f,0.f,0.f,0.f}, a1 = {0.f,0.f,0.f,0.f};
        for (int k0 = 0; k0 < I_SZ; k0 += 32) {
            bfrag bd = load_wfrag_f(drow + k0 + ko);
            bfrag h0 = *(const bfrag*)&Hs2[lr][k0 + ko];
            bfrag h1 = *(const bfrag*)&Hs2[lr + 16][k0 + ko];
            a0 = MFMA16(h0, bd, a0);
            a1 = MFMA16(h1, bd, a1);
        }
        #pragma unroll
        for (int r = 0; r < 4; ++r) {
            const int trow = lq * 4 + r;
            float w0 = tws[trow], w1 = tws[trow + 16];
            if (w0 != 0.f) atomicAdd(out + (size_t)toks[trow] * H_DIM + c0 + lr, a0[r] * w0);
            if (w1 != 0.f) atomicAdd(out + (size_t)toks[trow + 16] * H_DIM + c0 + lr, a1[r] * w1);
        }
    }
}

// ---------------------------------------------------------------- launch
extern "C" void kernel_launch(void* const* d_in, const int* in_sizes, int n_in,
                              void* d_out, int out_size, void* d_ws, size_t ws_size,
                              hipStream_t stream) {
    const float* x     = (const float*)d_in[0];
    const float* rw    = (const float*)d_in[1];
    const float* ebias = (const float*)d_in[2];
    const float* gate_w = (const float*)d_in[3];
    const float* up_w   = (const float*)d_in[4];
    const float* down_w = (const float*)d_in[5];
    const float* shg    = (const float*)d_in[6];
    const float* shu    = (const float*)d_in[7];
    const float* shd    = (const float*)d_in[8];
    float* out = (float*)d_out;

    char* ws = (char*)d_ws;
    int*   counts = (int*)ws;                       // 64 B used
    int*   lists  = (int*)(ws + 1024);              // 16*2048 ints  = 128 KB
    float* lw     = (float*)(ws + 1024 + 131072);   // 16*2048 float = 128 KB
    size_t off = 1024 + 131072 + 131072;            // 263168

    const size_t n_gu = (size_t)E_EXP * I_SZ * H_DIM;   // 8388608
    const size_t n_sh = (size_t)H_DIM * 1024;           // 1048576
    const size_t n_x  = (size_t)T_TOK * H_DIM;          // 2097152

    short* g_bf  = (short*)(ws + off); off += n_gu * 2;
    short* u_bf  = (short*)(ws + off); off += n_gu * 2;
    short* d_bf  = (short*)(ws + off); off += n_gu * 2;
    short* sg_bf = (short*)(ws + off); off += n_sh * 2;
    short* su_bf = (short*)(ws + off); off += n_sh * 2;
    short* sd_bf = (short*)(ws + off); off += n_sh * 2;
    short* x_bf  = (short*)(ws + off); off += n_x * 2;
    short* h_r   = (short*)(ws + off); off += (size_t)E_EXP * T_TOK * I_SZ * 2;  // 32 MB
    short* h_sh  = (short*)(ws + off); off += (size_t)T_TOK * 1024 * 2;          // 4 MB
    const size_t need = off;

    if (ws_size >= need) {
        hipMemsetAsync(counts, 0, 64, stream);
        hipMemsetAsync(out, 0, (size_t)out_size * sizeof(float), stream);
        convert_all<<<14848, 256, 0, stream>>>(gate_w, up_w, down_w, shg, shu, shd, x,
                                               g_bf, u_bf, d_bf, sg_bf, su_bf, sd_bf, x_bf);
        router_kernel<<<T_TOK / RTOK, 256, 0, stream>>>(x, rw, ebias, counts, lists, lw);
        moe_gateup<<<4096 + 512, 256, 0, stream>>>(x_bf, counts, lists, g_bf, u_bf,
                                                   sg_bf, su_bf, h_r, h_sh);
        moe_down<<<8192 + 512, 256, 0, stream>>>(h_r, h_sh, counts, lists, lw,
                                                 d_bf, sd_bf, out);
    } else {
        zero_kernel<<<(out_size / 4 + 255) / 256, 256, 0, stream>>>(out, out_size / 4, counts);
        router_kernel<<<T_TOK / RTOK, 256, 0, stream>>>(x, rw, ebias, counts, lists, lw);
        moe_gemm_fb<<<(E_EXP + 2) * 64, 256, 0, stream>>>(x, gate_w, up_w, down_w,
                                                          shg, shu, shd, counts, lists, lw, out);
    }
}